// Round 1
// baseline (58.005 us; speedup 1.0000x reference)
//
#include <hip/hip_runtime.h>

#define B_ 4
#define H_ 68
#define W_ 120
#define J_ (H_*W_)            // 8160 cells per batch
#define HF 544
#define WF 960
#define TS 32
#define TXN (WF/TS)           // 30
#define TYN (HF/TS)           // 17
#define NTILE (B_*TXN*TYN)    // 2040
#define CAPMAX 512

// ws layout:
//   float4 cdata[B_*J_]            : 32640*16 = 522240 B
//   int    counts[NTILE]           : 2040*4*4 = 32640 B  (actually B*TYN*TXN = 2040)
//   int    lists[NTILE*cap]
#define CDATA_BYTES (B_*J_*16)
#define COUNT_BYTES (NTILE*4)

// Phase 1: per-cell binning. Each active cell appends its index to all tiles
// within its truncation radius r = sqrt(2*var*ln(conf*1e5)).
__global__ __launch_bounds__(256) void pif_bin(const float* __restrict__ mean,
                                               const float* __restrict__ var,
                                               const float* __restrict__ conf,
                                               float4* __restrict__ cdata,
                                               int* __restrict__ counts,
                                               int* __restrict__ lists,
                                               int cap) {
    int gid = blockIdx.x * 256 + threadIdx.x;
    if (gid >= B_ * J_) return;
    int b = gid / J_;
    int j = gid - b * J_;

    float mx = mean[2 * gid + 0];
    float my = mean[2 * gid + 1];
    float v  = var[gid];
    float cf = conf[gid];
    float iv = 1.0f / (2.0f * v);
    cdata[gid] = make_float4(mx, my, iv, cf);

    if (!(cf > 0.1f)) return;   // thresholded cells contribute exactly 0

    // cut where conf*exp(-d^2 * iv) < 1e-5  ->  d^2 > 2*var*ln(conf*1e5)
    float lc = __logf(cf * 1e5f);           // conf>0.1 -> lc in [9.2, 11.5]
    float r  = sqrtf(fmaxf(2.0f * v * lc, 0.0f));

    int tx0 = max(0,       (int)floorf((mx - r) * (1.0f / TS)));
    int tx1 = min(TXN - 1, (int)floorf((mx + r) * (1.0f / TS)));
    int ty0 = max(0,       (int)floorf((my - r) * (1.0f / TS)));
    int ty1 = min(TYN - 1, (int)floorf((my + r) * (1.0f / TS)));

    for (int ty = ty0; ty <= ty1; ++ty) {
        for (int tx = tx0; tx <= tx1; ++tx) {
            int t = (b * TYN + ty) * TXN + tx;
            int idx = atomicAdd(&counts[t], 1);
            if (idx < cap) lists[(size_t)t * cap + idx] = j;
        }
    }
}

// Phase 2: one 256-thread block per 32x32 tile. Thread (lg, lx) owns pixels
// (y0+lg+8k, x0+lx), k=0..3. Cells processed 8 at a time: threads cooperatively
// build separable factors ex[8][32] (conf folded in) and ey[8][32] in LDS,
// then FMA-accumulate via broadcast LDS reads.
__global__ __launch_bounds__(256) void pif_accum(const float4* __restrict__ cdata,
                                                 const int* __restrict__ counts,
                                                 const int* __restrict__ lists,
                                                 float* __restrict__ out,
                                                 int cap) {
    int tx = blockIdx.x, ty = blockIdx.y, b = blockIdx.z;
    int tid = threadIdx.x;
    int lx = tid & 31;        // column within tile (also used as row index i
    int lg = tid >> 5;        // 0..7           when building the ey table)

    __shared__ float4 cellLDS[256];
    __shared__ float  exL[8][32];
    __shared__ float  eyL[8][32];

    int tileId = (b * TYN + ty) * TXN + tx;
    int count = counts[tileId];
    if (count > cap) count = cap;
    const int* list = lists + (size_t)tileId * cap;

    float x0 = (float)(tx * TS);
    float y0 = (float)(ty * TS);

    float acc0 = 0.f, acc1 = 0.f, acc2 = 0.f, acc3 = 0.f;

    for (int base = 0; base < count; base += 256) {
        int n = count - base;
        if (n > 256) n = 256;
        // stage this chunk's cell data into LDS (zero-pad the tail: cf=0 -> ex=0)
        if (tid < n) {
            cellLDS[tid] = cdata[(size_t)b * J_ + list[base + tid]];
        } else {
            cellLDS[tid] = make_float4(0.f, 0.f, 0.f, 0.f);
        }
        __syncthreads();

        int nsub = (n + 7) >> 3;
        for (int s = 0; s < nsub; ++s) {
            // build separable factors for cells [8s, 8s+8): thread computes
            // cell c=lg, index i=lx for both the x-table and the y-table.
            float4 cd = cellLDS[s * 8 + lg];
            float dx = (x0 + (float)lx) - cd.x;
            float dy = (y0 + (float)lx) - cd.y;
            exL[lg][lx] = cd.w * __expf(-dx * dx * cd.z);
            eyL[lg][lx] = __expf(-dy * dy * cd.z);
            __syncthreads();

            #pragma unroll
            for (int c = 0; c < 8; ++c) {
                float exv = exL[c][lx];
                float e0 = eyL[c][lg];
                float e1 = eyL[c][lg + 8];
                float e2 = eyL[c][lg + 16];
                float e3 = eyL[c][lg + 24];
                acc0 = fmaf(e0, exv, acc0);
                acc1 = fmaf(e1, exv, acc1);
                acc2 = fmaf(e2, exv, acc2);
                acc3 = fmaf(e3, exv, acc3);
            }
            __syncthreads();
        }
    }

    int xo = tx * TS + lx;
    int yo = ty * TS + lg;
    size_t o = ((size_t)(b * HF + yo)) * WF + xo;
    out[o]            = acc0;
    out[o +  8 * WF]  = acc1;
    out[o + 16 * WF]  = acc2;
    out[o + 24 * WF]  = acc3;
}

extern "C" void kernel_launch(void* const* d_in, const int* in_sizes, int n_in,
                              void* d_out, int out_size, void* d_ws, size_t ws_size,
                              hipStream_t stream) {
    const float* mean = (const float*)d_in[0];
    const float* var  = (const float*)d_in[1];
    const float* conf = (const float*)d_in[2];
    float* out = (float*)d_out;

    char* ws = (char*)d_ws;
    float4* cdata = (float4*)ws;
    int* counts   = (int*)(ws + CDATA_BYTES);
    int* lists    = (int*)(ws + CDATA_BYTES + COUNT_BYTES);

    size_t fixed = (size_t)CDATA_BYTES + COUNT_BYTES;
    size_t avail = (ws_size > fixed) ? (ws_size - fixed) : 0;
    size_t cap_s = avail / ((size_t)NTILE * 4);
    int cap = (cap_s > CAPMAX) ? CAPMAX : (int)cap_s;
    if (cap < 1) cap = 1;  // degenerate ws; nothing better we can do

    hipMemsetAsync(counts, 0, COUNT_BYTES, stream);

    int nthreads = B_ * J_;
    pif_bin<<<(nthreads + 255) / 256, 256, 0, stream>>>(mean, var, conf,
                                                        cdata, counts, lists, cap);

    pif_accum<<<dim3(TXN, TYN, B_), 256, 0, stream>>>(cdata, counts, lists, out, cap);
}